// Round 2
// baseline (139.838 us; speedup 1.0000x reference)
//
#include <hip/hip_runtime.h>
#include <math.h>

#define DD 160
#define HH 192
#define WW 160
#define TW 32          // block tile width  (full 32-lane rows => 0-conflict LDS)
#define THB 16         // block tile height (4 waves x 2 rows x 2 voxels)
#define TD 4           // slices per block (R9: 8->4 doubles grid to 2400 blocks
                       // -> 9.4 blocks/CU demand vs 4.7; latency-bound fix)
#define HW (HH * WW)
#define NVOX (DD * HW)
#define HTW 34         // halo cols
#define HTH 18         // halo rows
#define LSTR 34        // row stride: each 32-lane phase = one row = all 32 banks once
#define HALO (HTH * HTW)   // 612

typedef float v2f __attribute__((ext_vector_type(2)));

__device__ __forceinline__ v2f vrcp(v2f a) {
    v2f r;
    r.x = __builtin_amdgcn_rcpf(a.x);
    r.y = __builtin_amdgcn_rcpf(a.y);
    return r;
}

// packed atan(num/den) with a SINGLE rcp: x = min(|n|,|d|) * rcp(max(|n|,|d|)),
// odd minimax poly on [0,1], quadrant select on |n|>|d|, sign = sgn(n)^sgn(d).
// Replaces rcp(den)+mul+rcp(|r|) (3 packed rcp per atan-pair) with 1 per atan.
// err ~1e-5 rad, averages out over the 4.9M-voxel mean.
__device__ __forceinline__ v2f atan_ratio(v2f num, v2f den) {
    v2f a = __builtin_elementwise_abs(num);
    v2f b = __builtin_elementwise_abs(den);
    v2f mn = __builtin_elementwise_min(a, b);
    v2f mx = __builtin_elementwise_max(a, b);
    v2f x = mn * vrcp(mx);
    v2f x2 = x * x;
    v2f p = __builtin_elementwise_fma(x2,
            __builtin_elementwise_fma(x2,
            __builtin_elementwise_fma(x2,
            __builtin_elementwise_fma(x2,
            __builtin_elementwise_fma(x2, (v2f)(-0.0117212f), (v2f)(0.05265332f)),
            (v2f)(-0.11643287f)), (v2f)(0.19354346f)), (v2f)(-0.33262347f)),
            (v2f)(0.99997726f));
    p *= x;
    v2f q = 1.57079632679489662f - p;
    v2f res;
    res.x = a.x > b.x ? q.x : p.x;   // res >= 0 here
    res.y = a.y > b.y ? q.y : p.y;
    unsigned sx = (__float_as_uint(num.x) ^ __float_as_uint(den.x)) & 0x80000000u;
    unsigned sy = (__float_as_uint(num.y) ^ __float_as_uint(den.y)) & 0x80000000u;
    res.x = __uint_as_float(__float_as_uint(res.x) | sx);
    res.y = __uint_as_float(__float_as_uint(res.y) | sy);
    return res;
}

// R4 structure (one barrier/stage, distance-1 named-scalar prefetch, 32-wide
// zero-conflict rows) + 2 h-adjacent voxels per thread computed as packed
// fp32 (v_pk_* on gfx950). NO min-waves cap (R8 lesson: forcing VGPR caused
// 14 MB of scratch spill).
__global__ __launch_bounds__(256) void demons_ori_kernel(
    const float* __restrict__ Mv, const float* __restrict__ Sv,
    const float* __restrict__ flow, float* __restrict__ out)
{
    __shared__ float buf[2][2][HTH * LSTR];   // [parity][field][h*LSTR+w]
    __shared__ float redbuf[4];

    const int tid = threadIdx.x;
    const int lane = tid & 63;
    const int wid = tid >> 6;
    const int tw = lane & 31;
    const int r  = wid * 4 + (lane >> 5) * 2;   // thread's first voxel row 0..15
    const int w0 = blockIdx.x * TW;
    const int h0 = blockIdx.y * THB;
    const int d0 = blockIdx.z * TD;

    // slice-invariant staging slots: tid, tid+256, tid+512 (612 total)
    const bool has2 = (tid < HALO - 512);   // tids 0..99
    int gb0, gb1, gb2 = 0;
    bool ok0, ok1, ok2 = false;
    {
        int i = tid;
        int hh = i / HTW, ww = i - HTW * hh;
        int gh = h0 + hh - 1, gw = w0 + ww - 1;
        ok0 = (gh >= 0 && gh < HH && gw >= 0 && gw < WW);
        gb0 = gh * WW + gw;
        i = tid + 256;
        hh = i / HTW; ww = i - HTW * hh;
        gh = h0 + hh - 1; gw = w0 + ww - 1;
        ok1 = (gh >= 0 && gh < HH && gw >= 0 && gw < WW);
        gb1 = gh * WW + gw;
        if (has2) {
            i = tid + 512;
            hh = i / HTW; ww = i - HTW * hh;
            gh = h0 + hh - 1; gw = w0 + ww - 1;
            ok2 = (gh >= 0 && gh < HH && gw >= 0 && gw < WW);
            gb2 = gh * WW + gw;
        }
    }

    // distance-1 prefetch set — named scalars only (round-3 lesson)
    float pS0 = 0.f, pM0 = 0.f, pS1 = 0.f, pM1 = 0.f, pS2 = 0.f, pM2 = 0.f;

    auto issue = [&](int d) {
        const bool din = (d >= 0) && (d < DD);
        const size_t base = (size_t)d * HW;
        pS0 = (din && ok0) ? Sv[base + gb0] : 0.f;
        pM0 = (din && ok0) ? Mv[base + gb0] : 0.f;
        pS1 = (din && ok1) ? Sv[base + gb1] : 0.f;
        pM1 = (din && ok1) ? Mv[base + gb1] : 0.f;
        pS2 = (din && ok2) ? Sv[base + gb2] : 0.f;
        pM2 = (din && ok2) ? Mv[base + gb2] : 0.f;
    };
    auto commit = [&](int d) {
        float* __restrict__ bS = &buf[d & 1][0][0];
        float* __restrict__ bM = &buf[d & 1][1][0];
        bS[tid] = pS0;        bM[tid] = pM0;
        bS[tid + 256] = pS1;  bM[tid + 256] = pM1;
        if (has2) { bS[tid + 512] = pS2; bM[tid + 512] = pM2; }
    };

    const int rb = r * LSTR + tw;   // stencil window rows r..r+3, cols tw..tw+2
    // separable in-plane partials for the 2-voxel pair; row sums shared.
    auto fieldPartials = [&](const float* __restrict__ b,
                             v2f& Px, v2f& Py, v2f& Bq, v2f& Cq) {
        const float* r0 = b + rb;
        const float* r1 = r0 + LSTR;
        const float* r2 = r1 + LSTR;
        const float* r3 = r2 + LSTR;
        float a0 = r0[0], b0 = r0[1], c0 = r0[2];
        float a1 = r1[0], b1 = r1[1], c1 = r1[2];
        float a2 = r2[0], b2 = r2[1], c2 = r2[2];
        float a3 = r3[0], b3 = r3[1], c3 = r3[2];
        float X0 = c0 - a0, X1 = c1 - a1, X2 = c2 - a2, X3 = c3 - a3;
        float W0 = a0 + 2.f * b0 + c0, W1 = a1 + 2.f * b1 + c1;
        float W2 = a2 + 2.f * b2 + c2, W3 = a3 + 2.f * b3 + c3;
        float I0 = a0 + b0 + c0, I1 = a1 + b1 + c1;
        float I2 = a2 + b2 + c2, I3 = a3 + b3 + c3;
        Px = (v2f){X0 + 2.f * X1 + X2, X1 + 2.f * X2 + X3};
        Py = (v2f){W2 - W0, W3 - W1};
        Bq = (v2f){I0 + 2.f * I1 + I2, I1 + 2.f * I2 + I3};
        Cq = (v2f){b1, b2};
    };

    // register ring: named v2f per slice {m,z,p} x field {S,M} x {Px,Py,B,C}
    v2f mSPx, mSPy, mSB, mSC, mMPx, mMPy, mMB, mMC;
    v2f zSPx, zSPy, zSB, zSC, zMPx, zMPy, zMB, zMC;
    v2f pSPx, pSPy, pSB, pSC, pMPx, pMPy, pMB, pMC;

    // ---- warmup (R4 sequence) ----
    issue(d0 - 1);
    commit(d0 - 1);          // only long exposed vmcnt wait of the block
    issue(d0);
    __syncthreads();
    fieldPartials(&buf[(d0 - 1) & 1][0][0], mSPx, mSPy, mSB, mSC);
    fieldPartials(&buf[(d0 - 1) & 1][1][0], mMPx, mMPy, mMB, mMC);
    commit(d0);
    issue(d0 + 1);
    __syncthreads();
    fieldPartials(&buf[d0 & 1][0][0], zSPx, zSPy, zSB, zSC);
    fieldPartials(&buf[d0 & 1][1][0], zMPx, zMPy, zMB, zMC);

    const size_t voffA = (size_t)(h0 + r) * WW + (w0 + tw);   // voxel A; B = +WW
    v2f fFx, fFy, fFz;
    {
        size_t o = (size_t)d0 * HW + voffA;
        fFx = (v2f){flow[o], flow[o + WW]};
        fFy = (v2f){flow[NVOX + o], flow[NVOX + o + WW]};
        fFz = (v2f){flow[2 * (size_t)NVOX + o], flow[2 * (size_t)NVOX + o + WW]};
    }

    v2f vsum = (v2f){0.f, 0.f};

    #pragma unroll
    for (int dd = 0; dd < TD; ++dd) {
        const int d = d0 + dd;
        commit(d + 1);       // vmcnt wait for loads issued one stage ago
        v2f nFx = (v2f){0.f, 0.f}, nFy = nFx, nFz = nFx;
        if (dd < TD - 1) {
            issue(d + 2);    // in flight across this whole stage
            size_t o = (size_t)(d + 1) * HW + voffA;
            nFx = (v2f){flow[o], flow[o + WW]};
            nFy = (v2f){flow[NVOX + o], flow[NVOX + o + WW]};
            nFz = (v2f){flow[2 * (size_t)NVOX + o], flow[2 * (size_t)NVOX + o + WW]};
        }
        __syncthreads();
        fieldPartials(&buf[(d + 1) & 1][0][0], pSPx, pSPy, pSB, pSC);
        fieldPartials(&buf[(d + 1) & 1][1][0], pMPx, pMPy, pMB, pMC);

        v2f idf = zMC - zSC;
        v2f i2  = __builtin_elementwise_fma(idf, idf, (v2f)(1e-10f));
        v2f gxS = mSPx + zSPx + pSPx;
        v2f gyS = mSPy + zSPy + pSPy;
        v2f gzS = pSB - mSB;
        v2f gxM = mMPx + zMPx + pMPx;
        v2f gyM = mMPy + zMPy + pMPy;
        v2f gzM = pMB - mMB;
        v2f denS = __builtin_elementwise_fma(gxS, gxS,
                   __builtin_elementwise_fma(gyS, gyS,
                   __builtin_elementwise_fma(gzS, gzS, i2)));
        v2f denM = __builtin_elementwise_fma(gxM, gxM,
                   __builtin_elementwise_fma(gyM, gyM,
                   __builtin_elementwise_fma(gzM, gzM, i2)));
        v2f rS = vrcp(denS);
        v2f rM = vrcp(denM);
        v2f Ux = idf * __builtin_elementwise_fma(gxS, rS, gxM * rM);
        v2f Uy = idf * __builtin_elementwise_fma(gyS, rS, gyM * rM);
        v2f Uz = idf * __builtin_elementwise_fma(gzS, rS, gzM * rM);

        v2f uzp = Uz + 1e-10f;
        v2f dxz = atan_ratio(Ux, uzp);
        v2f dyz = atan_ratio(Uy, uzp);

        v2f fzp = fFz + 1e-10f;
        v2f fxz = atan_ratio(fFx, fzp);
        v2f fyz = atan_ratio(fFy, fzp);

        v2f e1 = fxz - dxz;
        v2f e2 = fyz - dyz;
        vsum = __builtin_elementwise_fma(e1, e1,
               __builtin_elementwise_fma(e2, e2, vsum));

        // rotate ring (renamed by full unroll)
        mSPx = zSPx; mSPy = zSPy; mSB = zSB; mSC = zSC;
        mMPx = zMPx; mMPy = zMPy; mMB = zMB; mMC = zMC;
        zSPx = pSPx; zSPy = pSPy; zSB = pSB; zSC = pSC;
        zMPx = pMPx; zMPy = pMPy; zMB = pMB; zMC = pMC;
        fFx = nFx; fFy = nFy; fFz = nFz;
    }

    float lsum = vsum.x + vsum.y;
    // wave shuffle reduce -> per-wave LDS slot -> one atomic per block
    #pragma unroll
    for (int o = 32; o > 0; o >>= 1)
        lsum += __shfl_down(lsum, o, 64);
    if (lane == 0)
        redbuf[wid] = lsum;
    __syncthreads();
    if (tid == 0) {
        float s = redbuf[0] + redbuf[1] + redbuf[2] + redbuf[3];
        atomicAdd(out, s * (1.0f / (float)NVOX));
    }
}

extern "C" void kernel_launch(void* const* d_in, const int* in_sizes, int n_in,
                              void* d_out, int out_size, void* d_ws, size_t ws_size,
                              hipStream_t stream) {
    const float* Mv   = (const float*)d_in[0];
    const float* Sv   = (const float*)d_in[1];
    const float* flow = (const float*)d_in[2];
    float* out = (float*)d_out;

    hipMemsetAsync(out, 0, sizeof(float), stream);

    dim3 grid(WW / TW, HH / THB, DD / TD);   // 5 x 12 x 40 = 2400 blocks
    demons_ori_kernel<<<grid, dim3(256), 0, stream>>>(Mv, Sv, flow, out);
}

// Round 3
// 129.542 us; speedup vs baseline: 1.0795x; 1.0795x over previous
//
#include <hip/hip_runtime.h>
#include <math.h>

#define DD 160
#define HH 192
#define WW 160
#define TW 32          // block tile width
#define THB 16         // block tile height (16 rows x 16 w-pairs = 256 threads)
#define TD 8           // R2 lesson: TD=4 regressed (total block-stages +20%,
                       // residency did NOT scale with grid). Keep 8.
#define HW (HH * WW)
#define NVOX (DD * HW)
#define HTW 34         // halo cols
#define HTH 18         // halo rows
#define LSTR 34        // row stride == HTW keeps staging LINEAR (bS[tid])
#define HALO (HTH * HTW)   // 612

typedef float v2f __attribute__((ext_vector_type(2)));

__device__ __forceinline__ v2f vrcp(v2f a) {
    v2f r;
    r.x = __builtin_amdgcn_rcpf(a.x);
    r.y = __builtin_amdgcn_rcpf(a.y);
    return r;
}

// packed atan(num/den) with a SINGLE rcp: x = min(|n|,|d|) * rcp(max(|n|,|d|)),
// odd minimax poly on [0,1], quadrant select on |n|>|d|, sign = sgn(n)^sgn(d).
// err ~1e-5 rad, averages out over the 4.9M-voxel mean.
__device__ __forceinline__ v2f atan_ratio(v2f num, v2f den) {
    v2f a = __builtin_elementwise_abs(num);
    v2f b = __builtin_elementwise_abs(den);
    v2f mn = __builtin_elementwise_min(a, b);
    v2f mx = __builtin_elementwise_max(a, b);
    v2f x = mn * vrcp(mx);
    v2f x2 = x * x;
    v2f p = __builtin_elementwise_fma(x2,
            __builtin_elementwise_fma(x2,
            __builtin_elementwise_fma(x2,
            __builtin_elementwise_fma(x2,
            __builtin_elementwise_fma(x2, (v2f)(-0.0117212f), (v2f)(0.05265332f)),
            (v2f)(-0.11643287f)), (v2f)(0.19354346f)), (v2f)(-0.33262347f)),
            (v2f)(0.99997726f));
    p *= x;
    v2f q = 1.57079632679489662f - p;
    v2f res;
    res.x = a.x > b.x ? q.x : p.x;   // res >= 0 here
    res.y = a.y > b.y ? q.y : p.y;
    unsigned sx = (__float_as_uint(num.x) ^ __float_as_uint(den.x)) & 0x80000000u;
    unsigned sy = (__float_as_uint(num.y) ^ __float_as_uint(den.y)) & 0x80000000u;
    res.x = __uint_as_float(__float_as_uint(res.x) | sx);
    res.y = __uint_as_float(__float_as_uint(res.y) | sy);
    return res;
}

// R10: w-adjacent voxel pair (was h-adjacent). Cuts per-stage instruction
// counts: LDS reads 24 scalar -> 6x 8B (ds_read2_b64-mergeable), flow loads
// 6 dword -> 3 dwordx2, horizontal filter math fully packed (v_pk_*).
// R2 evidence: kernel time identical with L3-resident inputs -> issue-bound,
// not BW-bound; residency doesn't scale with grid -> shrink work per stage.
__global__ __launch_bounds__(256) void demons_ori_kernel(
    const float* __restrict__ Mv, const float* __restrict__ Sv,
    const float* __restrict__ flow, float* __restrict__ out)
{
    __shared__ float buf[2][2][HTH * LSTR];   // [parity][field][h*LSTR+w]
    __shared__ float redbuf[4];

    const int tid = threadIdx.x;
    const int lane = tid & 63;
    const int wid = tid >> 6;
    const int i16 = lane & 15;                  // w-pair index 0..15
    const int r   = wid * 4 + (lane >> 4);      // voxel row 0..15
    const int tw2 = 2 * i16;                    // block-local first col of pair
    const int w0 = blockIdx.x * TW;
    const int h0 = blockIdx.y * THB;
    const int d0 = blockIdx.z * TD;

    // slice-invariant staging slots: tid, tid+256, tid+512 (612 total)
    const bool has2 = (tid < HALO - 512);   // tids 0..99
    int gb0, gb1, gb2 = 0;
    bool ok0, ok1, ok2 = false;
    {
        int i = tid;
        int hh = i / HTW, ww = i - HTW * hh;
        int gh = h0 + hh - 1, gw = w0 + ww - 1;
        ok0 = (gh >= 0 && gh < HH && gw >= 0 && gw < WW);
        gb0 = gh * WW + gw;
        i = tid + 256;
        hh = i / HTW; ww = i - HTW * hh;
        gh = h0 + hh - 1; gw = w0 + ww - 1;
        ok1 = (gh >= 0 && gh < HH && gw >= 0 && gw < WW);
        gb1 = gh * WW + gw;
        if (has2) {
            i = tid + 512;
            hh = i / HTW; ww = i - HTW * hh;
            gh = h0 + hh - 1; gw = w0 + ww - 1;
            ok2 = (gh >= 0 && gh < HH && gw >= 0 && gw < WW);
            gb2 = gh * WW + gw;
        }
    }

    // distance-1 prefetch set — named scalars only (round-3 lesson)
    float pS0 = 0.f, pM0 = 0.f, pS1 = 0.f, pM1 = 0.f, pS2 = 0.f, pM2 = 0.f;

    auto issue = [&](int d) {
        const bool din = (d >= 0) && (d < DD);
        const size_t base = (size_t)d * HW;
        pS0 = (din && ok0) ? Sv[base + gb0] : 0.f;
        pM0 = (din && ok0) ? Mv[base + gb0] : 0.f;
        pS1 = (din && ok1) ? Sv[base + gb1] : 0.f;
        pM1 = (din && ok1) ? Mv[base + gb1] : 0.f;
        pS2 = (din && ok2) ? Sv[base + gb2] : 0.f;
        pM2 = (din && ok2) ? Mv[base + gb2] : 0.f;
    };
    auto commit = [&](int d) {
        float* __restrict__ bS = &buf[d & 1][0][0];
        float* __restrict__ bM = &buf[d & 1][1][0];
        bS[tid] = pS0;        bM[tid] = pM0;
        bS[tid + 256] = pS1;  bM[tid + 256] = pM1;
        if (has2) { bS[tid + 512] = pS2; bM[tid + 512] = pM2; }
    };

    // stencil window: halo rows r..r+2, halo cols tw2..tw2+3 (4 consecutive
    // floats per row = two 8B-aligned v2f loads -> ds_read2_b64)
    const int rb = r * LSTR + tw2;
    auto fieldPartials = [&](const float* __restrict__ b,
                             v2f& Px, v2f& Py, v2f& Bq, v2f& Cq) {
        const float* p0 = b + rb;
        const float* p1 = p0 + LSTR;
        const float* p2 = p1 + LSTR;
        v2f lo0 = *(const v2f*)p0, hi0 = *(const v2f*)(p0 + 2);
        v2f lo1 = *(const v2f*)p1, hi1 = *(const v2f*)(p1 + 2);
        v2f lo2 = *(const v2f*)p2, hi2 = *(const v2f*)(p2 + 2);
        // per-row horizontal windows for both voxels, packed:
        // X = [-1,0,1] -> {c-a, d-b};  W = [1,2,1];  I = [1,1,1]
        v2f X0 = hi0 - lo0, X1 = hi1 - lo1, X2 = hi2 - lo2;
        v2f m0 = (v2f){lo0.y, hi0.x};
        v2f m1 = (v2f){lo1.y, hi1.x};
        v2f m2 = (v2f){lo2.y, hi2.x};
        v2f s0 = lo0 + hi0, s1 = lo1 + hi1, s2 = lo2 + hi2;
        v2f W0 = __builtin_elementwise_fma(m0, (v2f)(2.f), s0);
        v2f W2 = __builtin_elementwise_fma(m2, (v2f)(2.f), s2);
        v2f I0 = s0 + m0, I1 = s1 + m1, I2 = s2 + m2;
        Px = __builtin_elementwise_fma(X1, (v2f)(2.f), X0) + X2;  // vert [1,2,1] of X
        Py = W2 - W0;                                             // vert [-1,0,1] of W
        Bq = __builtin_elementwise_fma(I1, (v2f)(2.f), I0) + I2;  // vert [1,2,1] of I
        Cq = m1;                                                  // center values
    };

    // register ring: named v2f per slice {m,z,p} x field {S,M} x {Px,Py,B,C}
    v2f mSPx, mSPy, mSB, mSC, mMPx, mMPy, mMB, mMC;
    v2f zSPx, zSPy, zSB, zSC, zMPx, zMPy, zMB, zMC;
    v2f pSPx, pSPy, pSB, pSC, pMPx, pMPy, pMB, pMC;

    // ---- warmup (R4 sequence) ----
    issue(d0 - 1);
    commit(d0 - 1);          // only long exposed vmcnt wait of the block
    issue(d0);
    __syncthreads();
    fieldPartials(&buf[(d0 - 1) & 1][0][0], mSPx, mSPy, mSB, mSC);
    fieldPartials(&buf[(d0 - 1) & 1][1][0], mMPx, mMPy, mMB, mMC);
    commit(d0);
    issue(d0 + 1);
    __syncthreads();
    fieldPartials(&buf[d0 & 1][0][0], zSPx, zSPy, zSB, zSC);
    fieldPartials(&buf[d0 & 1][1][0], zMPx, zMPy, zMB, zMC);

    const size_t voffA = (size_t)(h0 + r) * WW + (w0 + tw2);  // pair contiguous
    v2f fFx, fFy, fFz;
    {
        size_t o = (size_t)d0 * HW + voffA;
        fFx = *(const v2f*)(flow + o);
        fFy = *(const v2f*)(flow + NVOX + o);
        fFz = *(const v2f*)(flow + 2 * (size_t)NVOX + o);
    }

    v2f vsum = (v2f){0.f, 0.f};

    #pragma unroll
    for (int dd = 0; dd < TD; ++dd) {
        const int d = d0 + dd;
        commit(d + 1);       // vmcnt wait for loads issued one stage ago
        v2f nFx = (v2f){0.f, 0.f}, nFy = nFx, nFz = nFx;
        if (dd < TD - 1) {
            issue(d + 2);    // in flight across this whole stage
            size_t o = (size_t)(d + 1) * HW + voffA;
            nFx = *(const v2f*)(flow + o);
            nFy = *(const v2f*)(flow + NVOX + o);
            nFz = *(const v2f*)(flow + 2 * (size_t)NVOX + o);
        }
        __syncthreads();
        fieldPartials(&buf[(d + 1) & 1][0][0], pSPx, pSPy, pSB, pSC);
        fieldPartials(&buf[(d + 1) & 1][1][0], pMPx, pMPy, pMB, pMC);

        v2f idf = zMC - zSC;
        v2f i2  = __builtin_elementwise_fma(idf, idf, (v2f)(1e-10f));
        v2f gxS = mSPx + zSPx + pSPx;
        v2f gyS = mSPy + zSPy + pSPy;
        v2f gzS = pSB - mSB;
        v2f gxM = mMPx + zMPx + pMPx;
        v2f gyM = mMPy + zMPy + pMPy;
        v2f gzM = pMB - mMB;
        v2f denS = __builtin_elementwise_fma(gxS, gxS,
                   __builtin_elementwise_fma(gyS, gyS,
                   __builtin_elementwise_fma(gzS, gzS, i2)));
        v2f denM = __builtin_elementwise_fma(gxM, gxM,
                   __builtin_elementwise_fma(gyM, gyM,
                   __builtin_elementwise_fma(gzM, gzM, i2)));
        v2f rS = vrcp(denS);
        v2f rM = vrcp(denM);
        v2f Ux = idf * __builtin_elementwise_fma(gxS, rS, gxM * rM);
        v2f Uy = idf * __builtin_elementwise_fma(gyS, rS, gyM * rM);
        v2f Uz = idf * __builtin_elementwise_fma(gzS, rS, gzM * rM);

        v2f uzp = Uz + 1e-10f;
        v2f dxz = atan_ratio(Ux, uzp);
        v2f dyz = atan_ratio(Uy, uzp);

        v2f fzp = fFz + 1e-10f;
        v2f fxz = atan_ratio(fFx, fzp);
        v2f fyz = atan_ratio(fFy, fzp);

        v2f e1 = fxz - dxz;
        v2f e2 = fyz - dyz;
        vsum = __builtin_elementwise_fma(e1, e1,
               __builtin_elementwise_fma(e2, e2, vsum));

        // rotate ring (renamed by full unroll)
        mSPx = zSPx; mSPy = zSPy; mSB = zSB; mSC = zSC;
        mMPx = zMPx; mMPy = zMPy; mMB = zMB; mMC = zMC;
        zSPx = pSPx; zSPy = pSPy; zSB = pSB; zSC = pSC;
        zMPx = pMPx; zMPy = pMPy; zMB = pMB; zMC = pMC;
        fFx = nFx; fFy = nFy; fFz = nFz;
    }

    float lsum = vsum.x + vsum.y;
    // wave shuffle reduce -> per-wave LDS slot -> one atomic per block
    #pragma unroll
    for (int o = 32; o > 0; o >>= 1)
        lsum += __shfl_down(lsum, o, 64);
    if (lane == 0)
        redbuf[wid] = lsum;
    __syncthreads();
    if (tid == 0) {
        float s = redbuf[0] + redbuf[1] + redbuf[2] + redbuf[3];
        atomicAdd(out, s * (1.0f / (float)NVOX));
    }
}

extern "C" void kernel_launch(void* const* d_in, const int* in_sizes, int n_in,
                              void* d_out, int out_size, void* d_ws, size_t ws_size,
                              hipStream_t stream) {
    const float* Mv   = (const float*)d_in[0];
    const float* Sv   = (const float*)d_in[1];
    const float* flow = (const float*)d_in[2];
    float* out = (float*)d_out;

    hipMemsetAsync(out, 0, sizeof(float), stream);

    dim3 grid(WW / TW, HH / THB, DD / TD);   // 5 x 12 x 20 = 1200 blocks
    demons_ori_kernel<<<grid, dim3(256), 0, stream>>>(Mv, Sv, flow, out);
}